// Round 10
// baseline (409.079 us; speedup 1.0000x reference)
//
#include <hip/hip_runtime.h>
#include <hip/hip_bf16.h>
#include <cstdint>

using u16 = unsigned short;
using u32 = unsigned int;
using bf16x8 = __attribute__((ext_vector_type(8))) short;
using f32x4  = __attribute__((ext_vector_type(4))) float;

// Problem constants
#define NI 128
#define NC 128
#define RR 36
#define WW 50
#define DD 1024
#define LDC 6400        // = NC*WW
#define ATS 37          // aT row stride (floats), conflict-free
#define GEMM_BLOCKS 1800

#define GLL16(g, l) __builtin_amdgcn_global_load_lds(                        \
    (const __attribute__((address_space(1))) void*)(g),                      \
    (__attribute__((address_space(3))) void*)(l), 16, 0, 0)

// constant-address-space float: uniform loads select s_load (SGPR data)
typedef const __attribute__((address_space(4))) float cfloat;

__device__ __forceinline__ float2 bf16pair(u32 u) {
  float2 f;
  f.x = __uint_as_float(u << 16);
  f.y = __uint_as_float(u & 0xffff0000u);
  return f;
}

__device__ __forceinline__ u32 bf16_rne(u32 x) {
  return (x + 0x7FFFu + ((x >> 16) & 1u)) >> 16;
}

__device__ __forceinline__ uint4 pack8_bf16(float4 a, float4 b) {
  u16 o[8] = {(u16)bf16_rne(__float_as_uint(a.x)), (u16)bf16_rne(__float_as_uint(a.y)),
              (u16)bf16_rne(__float_as_uint(a.z)), (u16)bf16_rne(__float_as_uint(a.w)),
              (u16)bf16_rne(__float_as_uint(b.x)), (u16)bf16_rne(__float_as_uint(b.y)),
              (u16)bf16_rne(__float_as_uint(b.z)), (u16)bf16_rne(__float_as_uint(b.w))};
  return *(const uint4*)o;
}

// ---------------------------------------------------------------------------
// GEMM body, specialized at compile time on input dtype so the hot K-loop is
// BRANCH-FREE (round-8/9 put the dtype branch inside the K-loop: MfmaUtil
// 29% -> 14%, +90 us. Round 6's branch-free loop measured 84 us).
// XCD-region swizzle (round-9-verified: FETCH 305 -> 151 MB): xcd = id&7,
// 8 regions of 9 row-tiles x 25 col-tiles walked row-fastest.
// XOR-swizzled LDS (round-6-verified: 0 bank conflicts).
// ---------------------------------------------------------------------------
template <bool F32>
__device__ __forceinline__ void gemm_body(const void* __restrict__ im_in,
                                          const void* __restrict__ s_in,
                                          u16* __restrict__ raw,
                                          char* smem, int id, int t) {
  u16* As = (u16*)smem;              // 128 x 64 u16 = 16 KB
  u16* Bs = (u16*)(smem + 16384);    // 128 x 64 u16 = 16 KB
  const int lane = t & 63, wv = t >> 6;
  const int lm = lane & 15, q = lane >> 4;
  const int xcd = id & 7;
  const int j = id >> 3;             // 0..224
  const int row0 = ((xcd >> 1) * 9 + (j % 9)) * 128;
  const int col0 = ((xcd & 1) * 25 + (j / 9)) * 128;
  const int wm = wv >> 1, wn = wv & 1;
  f32x4 acc[4][4] = {};

  if constexpr (!F32) {
    const u16* A = (const u16*)im_in;
    const u16* B = (const u16*)s_in;
    const u16* ap[4];
    const u16* bp[4];
#pragma unroll
    for (int v = 0; v < 4; ++v) {
      int u = t + v * 256;
      int row = u >> 3;
      int ch = (u & 7) ^ (row & 7);        // inverse XOR swizzle on global side
      ap[v] = A + (size_t)(row0 + row) * DD + ch * 8;
      bp[v] = B + (size_t)(col0 + row) * DD + ch * 8;
    }
    for (int k0 = 0; k0 < DD; k0 += 64) {
#pragma unroll
      for (int v = 0; v < 4; ++v) GLL16(ap[v] + k0, &As[(t + v * 256) * 8]);
#pragma unroll
      for (int v = 0; v < 4; ++v) GLL16(bp[v] + k0, &Bs[(t + v * 256) * 8]);
      __syncthreads();
#pragma unroll
      for (int ks = 0; ks < 2; ++ks) {
        bf16x8 af[4], bf[4];
        const int pch = (ks * 4 + q) ^ (lm & 7);   // physical chunk
#pragma unroll
        for (int mi = 0; mi < 4; ++mi)
          af[mi] = *(const bf16x8*)&As[(wm * 64 + mi * 16 + lm) * 64 + pch * 8];
#pragma unroll
        for (int ni = 0; ni < 4; ++ni)
          bf[ni] = *(const bf16x8*)&Bs[(wn * 64 + ni * 16 + lm) * 64 + pch * 8];
#pragma unroll
        for (int mi = 0; mi < 4; ++mi)
#pragma unroll
          for (int ni = 0; ni < 4; ++ni)
            acc[mi][ni] = __builtin_amdgcn_mfma_f32_16x16x32_bf16(af[mi], bf[ni], acc[mi][ni], 0, 0, 0);
      }
      __syncthreads();
    }
  } else {
    const float* A = (const float*)im_in;
    const float* B = (const float*)s_in;
    const float* ap[4];
    const float* bp[4];
#pragma unroll
    for (int v = 0; v < 4; ++v) {
      int u = t + v * 256;
      int row = u >> 3;
      int ch = (u & 7) ^ (row & 7);
      ap[v] = A + (size_t)(row0 + row) * DD + ch * 8;
      bp[v] = B + (size_t)(col0 + row) * DD + ch * 8;
    }
    for (int k0 = 0; k0 < DD; k0 += 64) {
#pragma unroll
      for (int v = 0; v < 4; ++v) {
        const float* pa = ap[v] + k0;
        *(uint4*)&As[(t + v * 256) * 8] =
            pack8_bf16(*(const float4*)pa, *(const float4*)(pa + 4));
        const float* pb = bp[v] + k0;
        *(uint4*)&Bs[(t + v * 256) * 8] =
            pack8_bf16(*(const float4*)pb, *(const float4*)(pb + 4));
      }
      __syncthreads();
#pragma unroll
      for (int ks = 0; ks < 2; ++ks) {
        bf16x8 af[4], bf[4];
        const int pch = (ks * 4 + q) ^ (lm & 7);
#pragma unroll
        for (int mi = 0; mi < 4; ++mi)
          af[mi] = *(const bf16x8*)&As[(wm * 64 + mi * 16 + lm) * 64 + pch * 8];
#pragma unroll
        for (int ni = 0; ni < 4; ++ni)
          bf[ni] = *(const bf16x8*)&Bs[(wn * 64 + ni * 16 + lm) * 64 + pch * 8];
#pragma unroll
        for (int mi = 0; mi < 4; ++mi)
#pragma unroll
          for (int ni = 0; ni < 4; ++ni)
            acc[mi][ni] = __builtin_amdgcn_mfma_f32_16x16x32_bf16(af[mi], bf[ni], acc[mi][ni], 0, 0, 0);
      }
      __syncthreads();
    }
  }
#pragma unroll
  for (int mi = 0; mi < 4; ++mi)
#pragma unroll
    for (int ni = 0; ni < 4; ++ni)
#pragma unroll
      for (int v = 0; v < 4; ++v) {
        int rr = row0 + wm * 64 + mi * 16 + q * 4 + v;
        int cc = col0 + wn * 64 + ni * 16 + lm;
        raw[(size_t)rr * LDC + cc] = (u16)bf16_rne(__float_as_uint(acc[mi][ni][v]));
      }
}

// ---------------------------------------------------------------------------
// Kernel 1 (fused): blocks 0..1799 = GEMM (dtype-specialized bodies, uniform
// branch at entry only); blocks 1800..1927 = per-image Gram + w1 norms.
// Dtype sniff on im's first 4 KB; counter in smem[0] (LDS stays 32768 B,
// 5 blocks/CU). NO device-scope fences (round-7: ~330 us penalty).
// ---------------------------------------------------------------------------
__global__ __launch_bounds__(256) void fused_main(const void* __restrict__ im_in,
                                                  const void* __restrict__ s_in,
                                                  u16* __restrict__ raw,
                                                  float* __restrict__ G,
                                                  float* __restrict__ w1) {
  __shared__ __align__(16) char smem[32768];
  const int t = threadIdx.x;
  const int id = blockIdx.x;
  int* cntp = (int*)smem;
  if (t == 0) *cntp = 0;
  __syncthreads();
  {
    uint4 sv = *(const uint4*)((const u16*)im_in + t * 8);
    u32 ss[4] = {sv.x, sv.y, sv.z, sv.w};
    int local = 0;
#pragma unroll
    for (int e = 0; e < 4; ++e) {
      if (((ss[e] >> 7)  & 0xFF) >= 0xC0) local++;
      if (((ss[e] >> 23) & 0xFF) >= 0xC0) local++;
    }
    if (local) atomicAdd(cntp, local);
  }
  __syncthreads();
  const bool f32in = *cntp > 4;
  __syncthreads();   // everyone has read cnt before staging overwrites smem[0]

  const int lane = t & 63, wv = t >> 6;
  const int lm = lane & 15, q = lane >> 4;

  if (id < GEMM_BLOCKS) {
    if (!f32in) gemm_body<false>(im_in, s_in, raw, smem, id, t);
    else        gemm_body<true >(im_in, s_in, raw, smem, id, t);
  } else {
    // ---------------- Gram + w1 path ----------------
    const int b = id - GEMM_BLOCKS;
    u16* ims = (u16*)smem;               // 48 rows x 264 u16 = 25,344 B
    f32x4 acc[3][3] = {};

    for (int p = 0; p < 4; ++p) {
      const int kk = p * 256;
#pragma unroll
      for (int v = 0; v < 5; ++v) {
        int u = t + v * 256;
        if (u < 1152) {                  // 36 rows * 32 uint4
          int row = u >> 5;
          int kloc = (u & 31) * 8;
          uint4 val;
          if (!f32in) {
            val = *(const uint4*)((const u16*)im_in + (size_t)(b * RR + row) * DD + kk + kloc);
          } else {
            const float* p2 = (const float*)im_in + (size_t)(b * RR + row) * DD + kk + kloc;
            val = pack8_bf16(*(const float4*)p2, *(const float4*)(p2 + 4));
          }
          *(uint4*)&ims[row * 264 + kloc] = val;
        }
      }
      if (p == 0) {
#pragma unroll
        for (int v = 0; v < 2; ++v) {
          int u = t + v * 256;
          if (u < 396) {                 // 12 * 264 / 8
            uint4 z; z.x = 0; z.y = 0; z.z = 0; z.w = 0;
            *(uint4*)&ims[36 * 264 + u * 8] = z;
          }
        }
      }
      __syncthreads();
#pragma unroll
      for (int kq = 0; kq < 2; ++kq) {
        const int ks = wv * 2 + kq;
        bf16x8 af[3];
#pragma unroll
        for (int mi = 0; mi < 3; ++mi)
          af[mi] = *(const bf16x8*)&ims[(mi * 16 + lm) * 264 + ks * 32 + q * 8];
#pragma unroll
        for (int mi = 0; mi < 3; ++mi)
#pragma unroll
          for (int ni = 0; ni < 3; ++ni)
            acc[mi][ni] = __builtin_amdgcn_mfma_f32_16x16x32_bf16(af[mi], af[ni], acc[mi][ni], 0, 0, 0);
      }
      __syncthreads();
    }
    // cross-wave reduce (smem reused as float scratch: 3*2304*4 = 27,648 B)
    float* red = (float*)smem;
    if (wv > 0) {
#pragma unroll
      for (int mi = 0; mi < 3; ++mi)
#pragma unroll
        for (int ni = 0; ni < 3; ++ni)
#pragma unroll
          for (int v = 0; v < 4; ++v) {
            int row = mi * 16 + q * 4 + v;
            int col = ni * 16 + lm;
            red[(wv - 1) * 2304 + row * 48 + col] = acc[mi][ni][v];
          }
    }
    __syncthreads();
    if (wv == 0) {
#pragma unroll
      for (int mi = 0; mi < 3; ++mi)
#pragma unroll
        for (int ni = 0; ni < 3; ++ni)
#pragma unroll
          for (int v = 0; v < 4; ++v) {
            int row = mi * 16 + q * 4 + v;
            int col = ni * 16 + lm;
            float r0 = acc[mi][ni][v] + red[row * 48 + col] +
                       red[2304 + row * 48 + col] + red[4608 + row * 48 + col];
            if (row < RR && col < RR)
              G[(size_t)b * (RR * RR) + row * RR + col] = r0;
          }
    }
    // w1 rows for caption b
    for (int w = wv; w < WW; w += 4) {
      float sum = 0.f;
      if (!f32in) {
        const u16* sp = (const u16*)s_in + ((size_t)b * WW + w) * DD + lane * 16;
        uint4 A0 = *(const uint4*)sp;
        uint4 A1 = *(const uint4*)(sp + 8);
        u32 uu[8] = {A0.x, A0.y, A0.z, A0.w, A1.x, A1.y, A1.z, A1.w};
#pragma unroll
        for (int e = 0; e < 8; ++e) {
          float2 f = bf16pair(uu[e]);
          sum += f.x * f.x + f.y * f.y;
        }
      } else {
        const float* sp = (const float*)s_in + ((size_t)b * WW + w) * DD + lane * 16;
#pragma unroll
        for (int e = 0; e < 4; ++e) {
          float4 fv = *(const float4*)(sp + e * 4);
          sum += fv.x * fv.x + fv.y * fv.y + fv.z * fv.z + fv.w * fv.w;
        }
      }
#pragma unroll
      for (int off = 32; off > 0; off >>= 1) sum += __shfl_down(sum, off);
      if (lane == 0) w1[b * WW + w] = sqrtf(sum);
    }
  }
}

// ---------------------------------------------------------------------------
// Kernel 2: postproc, wave-per-(c,i) pair (round-5/6 verified form: AS(4)
// scalar-G path, NO fence / NO counter — fences regressed 5x in round 7).
// ---------------------------------------------------------------------------
__global__ __launch_bounds__(256, 2) void postproc(const u16* __restrict__ raw,
                                                   const float* __restrict__ G,
                                                   const float* __restrict__ w1,
                                                   const int* __restrict__ s_l,
                                                   float* __restrict__ scores) {
  const int i = blockIdx.y;
  const int wv = threadIdx.x >> 6;
  const int c = blockIdx.x * 4 + wv;
  const int lane = threadIdx.x & 63;
  __shared__ float aT[4][WW * ATS];         // 4 * 7400 B
  __shared__ float nrm9_s[4][RR];           // 576 B
  const int L = s_l[c];

  // ---- phase 1: lanes = regions ----
  if (lane < RR) {
    const u16* rp = raw + (size_t)(i * RR + lane) * LDC + c * WW;
    float sum = 0.f;
#pragma unroll
    for (int j = 0; j < 25; ++j) {
      float2 v = bf16pair(((const u32*)rp)[j]);
      float x0 = v.x > 0.f ? v.x : 0.1f * v.x;
      float x1 = v.y > 0.f ? v.y : 0.1f * v.y;
      if (2 * j     >= L) x0 = 0.f;
      if (2 * j + 1 >= L) x1 = 0.f;
      aT[wv][(2 * j) * ATS + lane]     = x0;
      aT[wv][(2 * j + 1) * ATS + lane] = x1;
      sum += x0 * x0 + x1 * x1;
    }
    nrm9_s[wv][lane] = 9.0f / (sqrtf(sum) + 1e-8f);
  }
  __syncthreads();

  // ---- phases 2-4: uniform flow, lanes = words (clamped) ----
  const int wIdx = lane < WW ? lane : WW - 1;
  const float* row = &aT[wv][wIdx * ATS];
  cfloat* Gp = (cfloat*)(G + (size_t)i * (RR * RR));

  float x[RR];
  float m = -1e30f;
#pragma unroll
  for (int r = 0; r < RR; ++r) {
    x[r] = row[r];
    m = fmaxf(m, x[r] * nrm9_s[wv][r]);
  }
  float e[RR];
  float sum = 0.f, w12r = 0.f;
#pragma unroll
  for (int r = 0; r < RR; ++r) {
    float er = __expf(x[r] * nrm9_s[wv][r] - m);
    e[r] = er;
    sum += er;
    w12r += er * (x[r] > 0.f ? x[r] : 10.0f * x[r]);   // inverse-leaky: raw value
  }
  float qq2 = 0.f;
#pragma unroll
  for (int r = 0; r < RR; ++r) {
    float h = 0.5f * Gp[r * RR + r] * e[r];
#pragma unroll
    for (int j = r + 1; j < RR; ++j)
      h += Gp[r * RR + j] * e[j];
    qq2 += e[r] * h;
  }
  float qq = 2.0f * qq2;
  float w1v = w1[c * WW + wIdx];
  float denom = fmaxf(w1v * sqrtf(fmaxf(qq, 0.f)), 1e-8f * sum);
  float rs = w12r / denom;
  float ew = (lane < L) ? __expf(6.0f * rs) : 0.f;
#pragma unroll
  for (int off = 32; off > 0; off >>= 1) ew += __shfl_down(ew, off);
  if (lane == 0) scores[i * NC + c] = logf(ew) * (1.0f / 6.0f);
}

// ---------------------------------------------------------------------------
// Kernel 3: hardest-negative contrastive loss over scores (128x128).
// ---------------------------------------------------------------------------
__global__ __launch_bounds__(128) void loss_k(const float* __restrict__ scores,
                                              u32* __restrict__ out) {
  __shared__ float diag[NI];
  __shared__ float red[NI];
  const int t = threadIdx.x;
  diag[t] = scores[t * NC + t];
  __syncthreads();
  const float di = diag[t];
  float rowmax = 0.f, colmax = 0.f;
  for (int k = 0; k < NC; ++k) {
    if (k != t) {
      float sr = scores[t * NC + k];
      rowmax = fmaxf(rowmax, fmaxf(0.2f + sr - di, 0.f));
      float sc = scores[k * NC + t];
      colmax = fmaxf(colmax, fmaxf(0.2f + sc - di, 0.f));
    }
  }
  red[t] = rowmax + colmax;
  __syncthreads();
  for (int st = 64; st > 0; st >>= 1) {
    if (t < st) red[t] += red[t + st];
    __syncthreads();
  }
  if (t == 0) {
    u32 b = bf16_rne(__float_as_uint(red[0]));
    out[0] = b | (b << 16);   // bf16 reader: low u16; fp32 reader: ~same value
  }
}

// ---------------------------------------------------------------------------
extern "C" void kernel_launch(void* const* d_in, const int* in_sizes, int n_in,
                              void* d_out, int out_size, void* d_ws, size_t ws_size,
                              hipStream_t stream) {
  const void* im_in = d_in[0];
  const void* s_in  = d_in[1];
  const int*  sl    = (const int*)d_in[2];

  char* ws = (char*)d_ws;
  u16*   raw    = (u16*)ws;                                  // 58,982,400 B (bf16)
  float* G      = (float*)(ws + 58982400);                   //    663,552 B
  float* w1     = G + 128 * RR * RR;                         //     25,600 B
  float* scores = w1 + NC * WW;                              //     65,536 B

  fused_main<<<dim3(GEMM_BLOCKS + 128), dim3(256), 0, stream>>>(
      im_in, s_in, raw, G, w1);
  postproc<<<dim3(32, 128), dim3(256), 0, stream>>>(raw, G, w1, sl, scores);
  loss_k<<<dim3(1), dim3(128), 0, stream>>>(scores, (u32*)d_out);
}

// Round 11
// 278.056 us; speedup vs baseline: 1.4712x; 1.4712x over previous
//
#include <hip/hip_runtime.h>
#include <hip/hip_bf16.h>
#include <cstdint>

using u16 = unsigned short;
using u32 = unsigned int;
using bf16x8 = __attribute__((ext_vector_type(8))) short;
using f32x4  = __attribute__((ext_vector_type(4))) float;

// Problem constants
#define NI 128
#define NC 128
#define RR 36
#define WW 50
#define DD 1024
#define LDC 6400   // = NC*WW
#define ATS 37     // aT row stride (floats), conflict-free
#define IMN ((size_t)NI * RR * DD)   // 4,718,592
#define SN  ((size_t)NC * WW * DD)   // 6,553,600

#define GLL16(g, l) __builtin_amdgcn_global_load_lds(                        \
    (const __attribute__((address_space(1))) void*)(g),                      \
    (__attribute__((address_space(3))) void*)(l), 16, 0, 0)

// constant-address-space float: uniform loads select s_load (SGPR data)
typedef const __attribute__((address_space(4))) float cfloat;

__device__ __forceinline__ float2 bf16pair(u32 u) {
  float2 f;
  f.x = __uint_as_float(u << 16);
  f.y = __uint_as_float(u & 0xffff0000u);
  return f;
}

__device__ __forceinline__ u32 bf16_rne(u32 x) {
  return (x + 0x7FFFu + ((x >> 16) & 1u)) >> 16;
}

// ---------------------------------------------------------------------------
// Kernel 0: convert + embedded dtype sniff (round-6 verified). Early-out
// when inputs are already bf16 (measured case) — downstream kernels then
// read the original input pointers directly.
// ---------------------------------------------------------------------------
__global__ __launch_bounds__(256) void convert_in(const void* __restrict__ im_in,
                                                  const void* __restrict__ s_in,
                                                  u16* __restrict__ imB,
                                                  u16* __restrict__ sB,
                                                  int* __restrict__ flag) {
  __shared__ int cnt;
  if (threadIdx.x == 0) cnt = 0;
  __syncthreads();
  const u16* imu = (const u16*)im_in;
  int local = 0;
#pragma unroll
  for (int v = 0; v < 16; ++v) {
    u16 u = imu[threadIdx.x * 16 + v];
    if (((u >> 7) & 0xFF) >= 0xC0) local++;
  }
  if (local) atomicAdd(&cnt, local);
  __syncthreads();
  const int f = (cnt > 4) ? 1 : 0;
  if (blockIdx.x == 0 && threadIdx.x == 0) *flag = f;
  if (!f) return;

  const size_t TOT8 = (IMN + SN) / 8;
  const size_t stride = (size_t)gridDim.x * blockDim.x;
  for (size_t g = (size_t)blockIdx.x * blockDim.x + threadIdx.x; g < TOT8; g += stride) {
    size_t base = g * 8;
    const u32* sp;
    u16* dst;
    if (base < IMN) { sp = (const u32*)im_in + base; dst = imB + base; }
    else            { sp = (const u32*)s_in + (base - IMN); dst = sB + (base - IMN); }
    u16 o[8];
#pragma unroll
    for (int e = 0; e < 8; ++e) o[e] = (u16)bf16_rne(sp[e]);
    *(uint4*)dst = *(const uint4*)o;
  }
}

// ---------------------------------------------------------------------------
// Kernel 1: per-image Gram G[i][r][r'] (MFMA, all 4 waves, K split 4-way)
// + caption word norms w1 folded in. One block per b = i = c. (Round-6 form.)
// ---------------------------------------------------------------------------
__global__ __launch_bounds__(256) void gram_w1(const u16* __restrict__ im_orig,
                                               const u16* __restrict__ im_conv,
                                               const u16* __restrict__ s_orig,
                                               const u16* __restrict__ s_conv,
                                               const int* __restrict__ flag,
                                               float* __restrict__ G,
                                               float* __restrict__ w1) {
  const u16* im = *flag ? im_conv : im_orig;
  const u16* s  = *flag ? s_conv : s_orig;
  __shared__ u16 ims[48 * 520];        // 49,920 B; reused as float scratch later
  const int b = blockIdx.x;
  const int t = threadIdx.x;
  const int lane = t & 63, wv = t >> 6;
  const int lm = lane & 15, q = lane >> 4;
  f32x4 acc[3][3] = {};

  for (int p = 0; p < 2; ++p) {
    const int kk = p * 512;
#pragma unroll
    for (int v = 0; v < 9; ++v) {
      int u = t + v * 256;          // 0..2303 = 36*64
      int row = u >> 6;
      int kloc = (u & 63) * 8;
      uint4 val = *(const uint4*)(im + (size_t)b * (RR * DD) + (size_t)row * DD + kk + kloc);
      *(uint4*)&ims[row * 520 + kloc] = val;
    }
    if (p == 0) {
#pragma unroll
      for (int v = 0; v < 4; ++v) {
        int u = t + v * 256;
        if (u < 780) {              // 12*520/8 = 780 uint4
          uint4 z; z.x = 0; z.y = 0; z.z = 0; z.w = 0;
          *(uint4*)&ims[36 * 520 + u * 8] = z;
        }
      }
    }
    __syncthreads();
#pragma unroll
    for (int kq = 0; kq < 4; ++kq) {
      const int ks = wv * 4 + kq;
      bf16x8 af[3];
#pragma unroll
      for (int mi = 0; mi < 3; ++mi)
        af[mi] = *(const bf16x8*)&ims[(mi * 16 + lm) * 520 + ks * 32 + q * 8];
#pragma unroll
      for (int mi = 0; mi < 3; ++mi)
#pragma unroll
        for (int ni = 0; ni < 3; ++ni)
          acc[mi][ni] = __builtin_amdgcn_mfma_f32_16x16x32_bf16(af[mi], af[ni], acc[mi][ni], 0, 0, 0);
    }
    __syncthreads();
  }
  float* red = (float*)ims;
  if (wv > 0) {
#pragma unroll
    for (int mi = 0; mi < 3; ++mi)
#pragma unroll
      for (int ni = 0; ni < 3; ++ni)
#pragma unroll
        for (int v = 0; v < 4; ++v) {
          int row = mi * 16 + q * 4 + v;
          int col = ni * 16 + lm;
          red[(wv - 1) * 2304 + row * 48 + col] = acc[mi][ni][v];
        }
  }
  __syncthreads();
  if (wv == 0) {
#pragma unroll
    for (int mi = 0; mi < 3; ++mi)
#pragma unroll
      for (int ni = 0; ni < 3; ++ni)
#pragma unroll
        for (int v = 0; v < 4; ++v) {
          int row = mi * 16 + q * 4 + v;
          int col = ni * 16 + lm;
          float r0 = acc[mi][ni][v] + red[row * 48 + col] +
                     red[2304 + row * 48 + col] + red[4608 + row * 48 + col];
          if (row < RR && col < RR)
            G[(size_t)b * (RR * RR) + row * RR + col] = r0;
        }
  }
  // w1 rows for caption b (no LDS dependency)
  const u16* sc = s + (size_t)b * WW * DD;
  for (int w = wv; w < WW; w += 4) {
    const u16* sp = sc + (size_t)w * DD + lane * 16;
    uint4 A0 = *(const uint4*)sp;
    uint4 A1 = *(const uint4*)(sp + 8);
    float sum = 0.f;
    u32 uu[8] = {A0.x, A0.y, A0.z, A0.w, A1.x, A1.y, A1.z, A1.w};
#pragma unroll
    for (int e = 0; e < 8; ++e) {
      float2 f = bf16pair(uu[e]);
      sum += f.x * f.x + f.y * f.y;
    }
#pragma unroll
    for (int off = 32; off > 0; off >>= 1) sum += __shfl_down(sum, off);
    if (lane == 0) w1[b * WW + w] = sqrtf(sum);
  }
}

// ---------------------------------------------------------------------------
// Kernel 2: STANDALONE gemm raw[ir][cw] (bf16 MFMA, bf16 out). Exact round-6
// form (84 us measured: branch-free K-loop, BK=64, XOR-swizzled LDS, 0 bank
// conflicts, VGPR 88) + the round-9-verified XCD-region swizzle (xcd=id&7;
// 8 regions of 9 row-tiles x 25 col-tiles, row-fastest walk) which halved
// FETCH in-context. Fusion experiments (r8-r10) all regressed 2-3x; keep
// this dispatch homogeneous.
// ---------------------------------------------------------------------------
__global__ __launch_bounds__(256) void gemm_raw(const u16* __restrict__ A_orig,
                                                const u16* __restrict__ A_conv,
                                                const u16* __restrict__ B_orig,
                                                const u16* __restrict__ B_conv,
                                                const int* __restrict__ flag,
                                                u16* __restrict__ C) {
  const u16* A = *flag ? A_conv : A_orig;
  const u16* B = *flag ? B_conv : B_orig;
  __shared__ u16 As[128 * 64];   // 16 KB
  __shared__ u16 Bs[128 * 64];   // 16 KB
  const int t = threadIdx.x;
  const int id = blockIdx.x;
  const int xcd = id & 7;
  const int j = id >> 3;             // 0..224
  const int row0 = ((xcd >> 1) * 9 + (j % 9)) * 128;
  const int col0 = ((xcd & 1) * 25 + (j / 9)) * 128;
  const int lane = t & 63, wv = t >> 6;
  const int wm = wv >> 1, wn = wv & 1;
  const int lm = lane & 15, q = lane >> 4;
  f32x4 acc[4][4] = {};

  // staging pointers with inverse-swizzled k-chunk
  const u16* ap[4];
  const u16* bp[4];
#pragma unroll
  for (int v = 0; v < 4; ++v) {
    int u = t + v * 256;
    int row = u >> 3;
    int c = (u & 7) ^ (row & 7);
    ap[v] = A + (size_t)(row0 + row) * DD + c * 8;
    bp[v] = B + (size_t)(col0 + row) * DD + c * 8;
  }

  for (int k0 = 0; k0 < DD; k0 += 64) {
#pragma unroll
    for (int v = 0; v < 4; ++v) GLL16(ap[v] + k0, &As[(t + v * 256) * 8]);
#pragma unroll
    for (int v = 0; v < 4; ++v) GLL16(bp[v] + k0, &Bs[(t + v * 256) * 8]);
    __syncthreads();
#pragma unroll
    for (int ks = 0; ks < 2; ++ks) {
      bf16x8 af[4], bf[4];
      const int pch = (ks * 4 + q) ^ (lm & 7);   // physical chunk
#pragma unroll
      for (int mi = 0; mi < 4; ++mi)
        af[mi] = *(const bf16x8*)&As[(wm * 64 + mi * 16 + lm) * 64 + pch * 8];
#pragma unroll
      for (int ni = 0; ni < 4; ++ni)
        bf[ni] = *(const bf16x8*)&Bs[(wn * 64 + ni * 16 + lm) * 64 + pch * 8];
#pragma unroll
      for (int mi = 0; mi < 4; ++mi)
#pragma unroll
        for (int ni = 0; ni < 4; ++ni)
          acc[mi][ni] = __builtin_amdgcn_mfma_f32_16x16x32_bf16(af[mi], bf[ni], acc[mi][ni], 0, 0, 0);
    }
    __syncthreads();
  }
#pragma unroll
  for (int mi = 0; mi < 4; ++mi)
#pragma unroll
    for (int ni = 0; ni < 4; ++ni)
#pragma unroll
      for (int v = 0; v < 4; ++v) {
        int rr = row0 + wm * 64 + mi * 16 + q * 4 + v;
        int cc = col0 + wn * 64 + ni * 16 + lm;
        C[(size_t)rr * LDC + cc] = (u16)bf16_rne(__float_as_uint(acc[mi][ni][v]));
      }
}

// ---------------------------------------------------------------------------
// Kernel 3: postproc, wave-per-(c,i) pair (round-5/6 verified form: AS(4)
// scalar-G path, NO fence / NO counter — fences regressed 5x in round 7).
// ---------------------------------------------------------------------------
__global__ __launch_bounds__(256, 2) void postproc(const u16* __restrict__ raw,
                                                   const float* __restrict__ G,
                                                   const float* __restrict__ w1,
                                                   const int* __restrict__ s_l,
                                                   float* __restrict__ scores) {
  const int i = blockIdx.y;
  const int wv = threadIdx.x >> 6;
  const int c = blockIdx.x * 4 + wv;
  const int lane = threadIdx.x & 63;
  __shared__ float aT[4][WW * ATS];         // 4 * 7400 B
  __shared__ float nrm9_s[4][RR];           // 576 B
  const int L = s_l[c];

  // ---- phase 1: lanes = regions ----
  if (lane < RR) {
    const u16* rp = raw + (size_t)(i * RR + lane) * LDC + c * WW;
    float sum = 0.f;
#pragma unroll
    for (int j = 0; j < 25; ++j) {
      float2 v = bf16pair(((const u32*)rp)[j]);
      float x0 = v.x > 0.f ? v.x : 0.1f * v.x;
      float x1 = v.y > 0.f ? v.y : 0.1f * v.y;
      if (2 * j     >= L) x0 = 0.f;
      if (2 * j + 1 >= L) x1 = 0.f;
      aT[wv][(2 * j) * ATS + lane]     = x0;
      aT[wv][(2 * j + 1) * ATS + lane] = x1;
      sum += x0 * x0 + x1 * x1;
    }
    nrm9_s[wv][lane] = 9.0f / (sqrtf(sum) + 1e-8f);
  }
  __syncthreads();

  // ---- phases 2-4: uniform flow, lanes = words (clamped) ----
  const int wIdx = lane < WW ? lane : WW - 1;
  const float* row = &aT[wv][wIdx * ATS];
  cfloat* Gp = (cfloat*)(G + (size_t)i * (RR * RR));

  float x[RR];
  float m = -1e30f;
#pragma unroll
  for (int r = 0; r < RR; ++r) {
    x[r] = row[r];
    m = fmaxf(m, x[r] * nrm9_s[wv][r]);
  }
  float e[RR];
  float sum = 0.f, w12r = 0.f;
#pragma unroll
  for (int r = 0; r < RR; ++r) {
    float er = __expf(x[r] * nrm9_s[wv][r] - m);
    e[r] = er;
    sum += er;
    w12r += er * (x[r] > 0.f ? x[r] : 10.0f * x[r]);   // inverse-leaky: raw value
  }
  float qq2 = 0.f;
#pragma unroll
  for (int r = 0; r < RR; ++r) {
    float h = 0.5f * Gp[r * RR + r] * e[r];
#pragma unroll
    for (int j = r + 1; j < RR; ++j)
      h += Gp[r * RR + j] * e[j];
    qq2 += e[r] * h;
  }
  float qq = 2.0f * qq2;
  float w1v = w1[c * WW + wIdx];
  float denom = fmaxf(w1v * sqrtf(fmaxf(qq, 0.f)), 1e-8f * sum);
  float rs = w12r / denom;
  float ew = (lane < L) ? __expf(6.0f * rs) : 0.f;
#pragma unroll
  for (int off = 32; off > 0; off >>= 1) ew += __shfl_down(ew, off);
  if (lane == 0) scores[i * NC + c] = logf(ew) * (1.0f / 6.0f);
}

// ---------------------------------------------------------------------------
// Kernel 4: hardest-negative contrastive loss over scores (128x128).
// ---------------------------------------------------------------------------
__global__ __launch_bounds__(128) void loss_k(const float* __restrict__ scores,
                                              u32* __restrict__ out) {
  __shared__ float diag[NI];
  __shared__ float red[NI];
  const int t = threadIdx.x;
  diag[t] = scores[t * NC + t];
  __syncthreads();
  const float di = diag[t];
  float rowmax = 0.f, colmax = 0.f;
  for (int k = 0; k < NC; ++k) {
    if (k != t) {
      float sr = scores[t * NC + k];
      rowmax = fmaxf(rowmax, fmaxf(0.2f + sr - di, 0.f));
      float sc = scores[k * NC + t];
      colmax = fmaxf(colmax, fmaxf(0.2f + sc - di, 0.f));
    }
  }
  red[t] = rowmax + colmax;
  __syncthreads();
  for (int st = 64; st > 0; st >>= 1) {
    if (t < st) red[t] += red[t + st];
    __syncthreads();
  }
  if (t == 0) {
    u32 b = bf16_rne(__float_as_uint(red[0]));
    out[0] = b | (b << 16);   // bf16 reader: low u16; fp32 reader: ~same value
  }
}

// ---------------------------------------------------------------------------
extern "C" void kernel_launch(void* const* d_in, const int* in_sizes, int n_in,
                              void* d_out, int out_size, void* d_ws, size_t ws_size,
                              hipStream_t stream) {
  const void* im_in = d_in[0];
  const void* s_in  = d_in[1];
  const int*  sl    = (const int*)d_in[2];

  char* ws = (char*)d_ws;
  u16*   imB    = (u16*)ws;                                  //  9,437,184 B
  u16*   sB     = (u16*)(ws + 9437184);                      // 13,107,200 B
  u16*   raw    = (u16*)(ws + 22544384);                     // 58,982,400 B (bf16)
  float* G      = (float*)(ws + 22544384 + 58982400);        //    663,552 B
  float* w1     = G + 128 * RR * RR;                         //     25,600 B
  float* scores = w1 + NC * WW;                              //     65,536 B
  int*   flag   = (int*)(scores + NI * NC);

  convert_in<<<dim3(2048), dim3(256), 0, stream>>>(im_in, s_in, imB, sB, flag);
  gram_w1<<<dim3(128), dim3(256), 0, stream>>>((const u16*)im_in, imB,
                                               (const u16*)s_in, sB, flag, G, w1);
  gemm_raw<<<dim3(1800), dim3(256), 0, stream>>>((const u16*)im_in, imB,
                                                 (const u16*)s_in, sB, flag, raw);
  postproc<<<dim3(32, 128), dim3(256), 0, stream>>>(raw, G, w1, sl, scores);
  loss_k<<<dim3(1), dim3(128), 0, stream>>>(scores, (u32*)d_out);
}